// Round 3
// baseline (224.949 us; speedup 1.0000x reference)
//
#include <hip/hip_runtime.h>

#define DM    512
#define NH    8
#define DH    64
#define SEQ   2048
#define PLEN  4095
#define NB    2
#define ATT_SCALE 0.125f

typedef __attribute__((ext_vector_type(8))) _Float16 half8;
typedef __attribute__((ext_vector_type(4))) float   floatx4;

__device__ __forceinline__ void gll16(const _Float16* g, _Float16* l) {
    __builtin_amdgcn_global_load_lds(
        (const __attribute__((address_space(1))) void*)g,
        (__attribute__((address_space(3))) void*)l, 16, 0, 0);
}

// ---------------------------------------------------------------------------
// prep: z=0 cast x -> x16; z=1 cast pe -> pe16; z=2..6 transpose+cast W
// ---------------------------------------------------------------------------
__global__ __launch_bounds__(256)
void prep(const float* __restrict__ x, const float* __restrict__ pe,
          const float* __restrict__ W0, const float* __restrict__ W1,
          const float* __restrict__ W2, const float* __restrict__ W3,
          const float* __restrict__ W4,
          _Float16* __restrict__ x16, _Float16* __restrict__ pe16,
          _Float16* __restrict__ Wt)
{
    __shared__ _Float16 tile[64 * 72];
    const int z = blockIdx.z;
    const int t = threadIdx.x;

    if (z < 2) {
        const float* src = z ? pe : x;
        _Float16* dst = z ? pe16 : x16;
        const long n = z ? (long)PLEN * DM : (long)NB * SEQ * DM;
        const long i = ((long)blockIdx.x * 256 + t) * 8;
        if (i >= n) return;
        float4 f0 = *(const float4*)(src + i);
        float4 f1 = *(const float4*)(src + i + 4);
        half8 o;
        o[0] = (_Float16)f0.x; o[1] = (_Float16)f0.y;
        o[2] = (_Float16)f0.z; o[3] = (_Float16)f0.w;
        o[4] = (_Float16)f1.x; o[5] = (_Float16)f1.y;
        o[6] = (_Float16)f1.z; o[7] = (_Float16)f1.w;
        *(half8*)(dst + i) = o;
        return;
    }
    if (blockIdx.x >= 64) return;
    const int wz = z - 2;
    const float* W = (wz == 0) ? W0 : (wz == 1) ? W1 : (wz == 2) ? W2
                   : (wz == 3) ? W3 : W4;
    _Float16* dst_base = Wt + (size_t)wz * DM * DM;
    const int n0 = (blockIdx.x & 7) * 64, k0 = (blockIdx.x >> 3) * 64;
    {
        const int kr = t >> 2, nch = (t & 3) * 16;
        const float* src = W + (size_t)(k0 + kr) * DM + n0 + nch;
        float4 f0 = *(const float4*)(src + 0);
        float4 f1 = *(const float4*)(src + 4);
        float4 f2 = *(const float4*)(src + 8);
        float4 f3 = *(const float4*)(src + 12);
        _Float16* trow = &tile[kr * 72 + nch];
        trow[0]  = (_Float16)f0.x; trow[1]  = (_Float16)f0.y;
        trow[2]  = (_Float16)f0.z; trow[3]  = (_Float16)f0.w;
        trow[4]  = (_Float16)f1.x; trow[5]  = (_Float16)f1.y;
        trow[6]  = (_Float16)f1.z; trow[7]  = (_Float16)f1.w;
        trow[8]  = (_Float16)f2.x; trow[9]  = (_Float16)f2.y;
        trow[10] = (_Float16)f2.z; trow[11] = (_Float16)f2.w;
        trow[12] = (_Float16)f3.x; trow[13] = (_Float16)f3.y;
        trow[14] = (_Float16)f3.z; trow[15] = (_Float16)f3.w;
    }
    __syncthreads();
    {
        const int nr = t >> 2, kch = (t & 3) * 16;
        half8 o0, o1;
#pragma unroll
        for (int i = 0; i < 8; ++i) o0[i] = tile[(kch + i) * 72 + nr];
#pragma unroll
        for (int i = 0; i < 8; ++i) o1[i] = tile[(kch + 8 + i) * 72 + nr];
        _Float16* dst = dst_base + (size_t)(n0 + nr) * DM + k0 + kch;
        *(half8*)dst = o0;
        *(half8*)(dst + 8) = o1;
    }
}

// ---------------------------------------------------------------------------
// Fused q/k/v/p projections with register-prefetch pipelining (unchanged).
// ---------------------------------------------------------------------------
__global__ __launch_bounds__(256)
void gemm_qkvp(const _Float16* __restrict__ X, const _Float16* __restrict__ Pe,
               const _Float16* __restrict__ Wt,
               const float* __restrict__ bq, const float* __restrict__ bk,
               const float* __restrict__ bv, const float* __restrict__ bu,
               const float* __restrict__ bvb,
               _Float16* __restrict__ qu16, _Float16* __restrict__ qv16,
               _Float16* __restrict__ k16, _Float16* __restrict__ vt16,
               _Float16* __restrict__ p16)
{
    __shared__ _Float16 aS[64 * 72];
    __shared__ _Float16 wS[64 * 72];

    const int t = threadIdx.x;
    const int w = t >> 6, lane = t & 63, quad = lane >> 4, l16 = lane & 15;
    const int z = blockIdx.z;
    const int n0 = blockIdx.x * 64;
    const int m0 = blockIdx.y * 64;
    const int srow = t >> 2, sch = (t & 3) * 16;
    const _Float16* A = (z == 3) ? Pe : X;
    const _Float16* Wz = Wt + (size_t)z * DM * DM;

    int arow = m0 + srow;
    if (z == 3 && arow > PLEN - 1) arow = PLEN - 1;   // clamp; store guarded
    const _Float16* arowp = A + (size_t)arow * DM + sch;
    const _Float16* wrowp = Wz + (size_t)(n0 + srow) * DM + sch;

    floatx4 acc[4];
#pragma unroll
    for (int ct = 0; ct < 4; ++ct) acc[ct] = (floatx4){0.f, 0.f, 0.f, 0.f};

    half8 pa0 = *(const half8*)arowp;
    half8 pa1 = *(const half8*)(arowp + 8);
    half8 pw0 = *(const half8*)wrowp;
    half8 pw1 = *(const half8*)(wrowp + 8);

    for (int k0 = 0; k0 < DM; k0 += 64) {
        __syncthreads();
        *(half8*)&aS[srow * 72 + sch]     = pa0;
        *(half8*)&aS[srow * 72 + sch + 8] = pa1;
        *(half8*)&wS[srow * 72 + sch]     = pw0;
        *(half8*)&wS[srow * 72 + sch + 8] = pw1;
        __syncthreads();
        if (k0 + 64 < DM) {
            pa0 = *(const half8*)(arowp + k0 + 64);
            pa1 = *(const half8*)(arowp + k0 + 72);
            pw0 = *(const half8*)(wrowp + k0 + 64);
            pw1 = *(const half8*)(wrowp + k0 + 72);
        }
#pragma unroll
        for (int kb = 0; kb < 2; ++kb) {
            half8 af = *(const half8*)&aS[(16 * w + l16) * 72 + kb * 32 + quad * 8];
#pragma unroll
            for (int ct = 0; ct < 4; ++ct) {
                half8 bf = *(const half8*)&wS[(16 * ct + l16) * 72 + kb * 32 + quad * 8];
                acc[ct] = __builtin_amdgcn_mfma_f32_16x16x32_f16(af, bf, acc[ct], 0, 0, 0);
            }
        }
    }

    const int h = n0 >> 6;
    if (z == 0) {
#pragma unroll
        for (int ct = 0; ct < 4; ++ct) {
            const int n = n0 + 16 * ct + l16;
            const float bval = bq[n], uval = bu[n], vval = bvb[n];
#pragma unroll
            for (int r = 0; r < 4; ++r) {
                const int m = m0 + 16 * w + 4 * quad + r;
                const int b = m >> 11, s = m & 2047;
                const size_t dst = ((size_t)((h * NB + b) * SEQ) + s) * DH + (n & 63);
                const float q = acc[ct][r] + bval;
                qu16[dst] = (_Float16)((q + uval) * ATT_SCALE);
                qv16[dst] = (_Float16)((q + vval) * ATT_SCALE);
            }
        }
    } else if (z == 1) {
#pragma unroll
        for (int ct = 0; ct < 4; ++ct) {
            const int n = n0 + 16 * ct + l16;
            const float bval = bk[n];
#pragma unroll
            for (int r = 0; r < 4; ++r) {
                const int m = m0 + 16 * w + 4 * quad + r;
                const int b = m >> 11, s = m & 2047;
                k16[((size_t)((h * NB + b) * SEQ) + s) * DH + (n & 63)] =
                    (_Float16)(acc[ct][r] + bval);
            }
        }
    } else if (z == 2) {
        __syncthreads();
#pragma unroll
        for (int ct = 0; ct < 4; ++ct) {
            const float bval = bv[n0 + 16 * ct + l16];
#pragma unroll
            for (int r = 0; r < 4; ++r)
                aS[(16 * w + 4 * quad + r) * 72 + 16 * ct + l16] =
                    (_Float16)(acc[ct][r] + bval);
        }
        __syncthreads();
        const int b = m0 >> 11, s0 = m0 & 2047;
        const int drow = t >> 2;
        half8 o0, o1;
#pragma unroll
        for (int i = 0; i < 8; ++i) o0[i] = aS[(sch + i) * 72 + drow];
#pragma unroll
        for (int i = 0; i < 8; ++i) o1[i] = aS[(sch + 8 + i) * 72 + drow];
        _Float16* dst = vt16 + ((size_t)((h * NB + b) * DH) + drow) * SEQ + s0 + sch;
        *(half8*)dst = o0;
        *(half8*)(dst + 8) = o1;
    } else {
#pragma unroll
        for (int ct = 0; ct < 4; ++ct) {
            const int n = n0 + 16 * ct + l16;
#pragma unroll
            for (int r = 0; r < 4; ++r) {
                const int m = m0 + 16 * w + 4 * quad + r;
                if (m < PLEN)
                    p16[((size_t)h * PLEN + m) * DH + (n & 63)] = (_Float16)acc[ct][r];
            }
        }
    }
}

// ---------------------------------------------------------------------------
// MFMA flash attention, rel-pos, no-max softmax, j-split 2-way.
// R3: P B-fragments loaded DIRECT global->register (one-tile prefetch placed
// after the gather where the previous frags die) -- removes the 32KB pS
// staging AND 10 of 28 b128 DS reads per wave-tile. K/V stay gll16-staged
// (double-buffered, XOR-swizzled). LDS 41.98KB -> 3 blocks/CU, 12 waves.
// DS model: 425 cyc/wave-tile -> per-CU 108.8k cyc = 45us at saturation.
// ---------------------------------------------------------------------------
__global__ __launch_bounds__(256, 3)
void relattn_mfma(const _Float16* __restrict__ QU,
                  const _Float16* __restrict__ QV,
                  const _Float16* __restrict__ Kp,
                  const _Float16* __restrict__ VT,
                  const _Float16* __restrict__ Pp,
                  float* __restrict__ Opart,
                  float* __restrict__ Lpart)
{
    // stage buffer: [2][ k:64x64 | v:64x64 ] halves, linear + XOR-swizzled
    __shared__ _Float16 sbuf[2][8192];
    __shared__ _Float16 tS[64 * 72];

    const int t = threadIdx.x;
    const int w = t >> 6, lane = t & 63, quad = lane >> 4, l16 = lane & 15;
    const int i0 = blockIdx.x * 64;
    const int h = blockIdx.y;
    const int b = blockIdx.z & 1, jh = blockIdx.z >> 1;
    const size_t hb = (size_t)(h * NB + b);
    const int cbase = 48 - 16 * w;
    const int jbeg = jh * (SEQ / 2), jend = jbeg + (SEQ / 2);

    half8 qa[2], va[2];
    {
        const _Float16* qrow = QU + (hb * SEQ + i0 + 16 * w + l16) * DH + quad * 8;
        const _Float16* vrow = QV + (hb * SEQ + i0 + 16 * w + l16) * DH + quad * 8;
        qa[0] = *(const half8*)qrow;       qa[1] = *(const half8*)(qrow + 32);
        va[0] = *(const half8*)vrow;       va[1] = *(const half8*)(vrow + 32);
    }

    floatx4 O[4];
    float lsum[4] = {0.f, 0.f, 0.f, 0.f};
#pragma unroll
    for (int ct = 0; ct < 4; ++ct) O[ct] = (floatx4){0.f, 0.f, 0.f, 0.f};

    const _Float16* Kbase = Kp + hb * SEQ * DH;
    const _Float16* Vbase = VT + hb * DH * SEQ;
    const int rbase0 = (SEQ - 1) - i0 - 63;   // P window base at j0=0

    // read-side swizzle constants: row&7 == l16&7 for every fragment read
    const int kx = l16 & 7;
    const int hox0 = ((quad) ^ kx) * 8;        // kb=0 chunk offset (halves)
    const int hox1 = ((4 + quad) ^ kx) * 8;    // kb=1

    // staging geometry (8 rows of 128B per gll16; lane -> row cid*8+(lane>>3))
    const int l3 = lane >> 3, pos = lane & 7;

#define STAGE_KV(bufp, J0)                                                     \
    {                                                                          \
        _Float16* bp = (bufp);                                                 \
        _Pragma("unroll")                                                      \
        for (int I = 0; I < 2; ++I) {                                          \
            const int cid = w * 2 + I;                                         \
            const int row = cid * 8 + l3;                                      \
            const int ch  = pos ^ (row & 7);                                   \
            gll16(Kbase + (size_t)((J0) + row) * DH + ch * 8, bp + cid * 512); \
        }                                                                      \
        _Pragma("unroll")                                                      \
        for (int I = 0; I < 2; ++I) {                                          \
            const int cid = w * 2 + I;                                         \
            const int row = cid * 8 + l3;                                      \
            const int ch  = pos ^ (row & 7);                                   \
            gll16(Vbase + (size_t)row * SEQ + (J0) + ch * 8,                   \
                  bp + 4096 + cid * 512);                                      \
        }                                                                      \
    }

    // P fragment pointer: row = rbase0 + j0 + cbase + 16*c2 + l16, col quad*8
    // (window-edge overrun reads <=1 row past p16 into allocated ow16; the
    //  gather provably never selects window col 79, so those lanes are dead)
    const _Float16* pptr = Pp + (size_t)h * PLEN * DH
                         + (size_t)(rbase0 + jbeg + cbase + l16) * DH + quad * 8;
    half8 pf0[5], pf1[5];

#define PLOAD()                                                                \
    {                                                                          \
        _Pragma("unroll")                                                      \
        for (int c2 = 0; c2 < 5; ++c2) {                                       \
            pf0[c2] = *(const half8*)(pptr + c2 * 1024);                       \
            pf1[c2] = *(const half8*)(pptr + c2 * 1024 + 32);                  \
        }                                                                      \
        pptr += 4096;                                                          \
    }

    // prologue: stage first K/V tile, prefetch first P fragments
    STAGE_KV(&sbuf[0][0], jbeg);
    PLOAD();

    int cur = 0;
    for (int j0 = jbeg; j0 < jend; j0 += 64) {
        asm volatile("s_waitcnt vmcnt(0)" ::: "memory");
        __builtin_amdgcn_s_barrier();
        asm volatile("" ::: "memory");

        const _Float16* kSc = &sbuf[cur][0];
        const _Float16* vSc = &sbuf[cur][4096];

        // issue next K/V tile's DMA (flies during compute)
        if (j0 + 64 < jend) STAGE_KV(&sbuf[cur ^ 1][0], j0 + 64);

        // ---- phase A: T = Qv @ Pwin^T from prefetched registers ----
        floatx4 Tacc[5];
#pragma unroll
        for (int c2 = 0; c2 < 5; ++c2) Tacc[c2] = (floatx4){0.f, 0.f, 0.f, 0.f};
#pragma unroll
        for (int c2 = 0; c2 < 5; ++c2) {
            Tacc[c2] = __builtin_amdgcn_mfma_f32_16x16x32_f16(va[0], pf0[c2], Tacc[c2], 0, 0, 0);
            Tacc[c2] = __builtin_amdgcn_mfma_f32_16x16x32_f16(va[1], pf1[c2], Tacc[c2], 0, 0, 0);
        }

        // ---- phase B: S = Qu @ K^T ----
        floatx4 Sc[4];
#pragma unroll
        for (int ct = 0; ct < 4; ++ct) Sc[ct] = (floatx4){0.f, 0.f, 0.f, 0.f};
#pragma unroll
        for (int ct = 0; ct < 4; ++ct) {
            half8 bf0 = *(const half8*)&kSc[(16 * ct + l16) * 64 + hox0];
            half8 bf1 = *(const half8*)&kSc[(16 * ct + l16) * 64 + hox1];
            Sc[ct] = __builtin_amdgcn_mfma_f32_16x16x32_f16(qa[0], bf0, Sc[ct], 0, 0, 0);
            Sc[ct] = __builtin_amdgcn_mfma_f32_16x16x32_f16(qa[1], bf1, Sc[ct], 0, 0, 0);
        }

        // ---- rel-shift gather from Tacc registers (fixed-quad 16-lane
        // rotation via ds_bpermute) + exp + lsum ----
#pragma unroll
        for (int r = 0; r < 4; ++r) {
            const int u  = l16 - 4 * quad - r + 15;   // [0,30]
            const int dl = u & 15;
            const int s  = u >> 4;                    // {0,1}
            const int pidx = (((quad << 4) | dl) << 2);
            float rot[5];
#pragma unroll
            for (int c2 = 0; c2 < 5; ++c2)
                rot[c2] = __int_as_float(__builtin_amdgcn_ds_bpermute(
                    pidx, __float_as_int(Tacc[c2][r])));
#pragma unroll
            for (int ct = 0; ct < 4; ++ct) {
                const float tv = s ? rot[ct + 1] : rot[ct];
                const float e = __expf(Sc[ct][r] + tv);
                Sc[ct][r] = e;
                lsum[r] += e;
            }
        }

        // ---- prefetch next tile's P fragments (old pf regs just died) ----
        if (j0 + 64 < jend) PLOAD();

        // ---- probs -> tS (wave-private rows) ----
#pragma unroll
        for (int ct = 0; ct < 4; ++ct)
#pragma unroll
            for (int r = 0; r < 4; ++r)
                tS[(16 * w + 4 * quad + r) * 72 + 16 * ct + l16] = (_Float16)Sc[ct][r];
        asm volatile("" ::: "memory");

        // ---- O += P @ V ----
#pragma unroll
        for (int kb = 0; kb < 2; ++kb) {
            half8 af = *(const half8*)&tS[(16 * w + l16) * 72 + kb * 32 + quad * 8];
            const int hox = kb ? hox1 : hox0;
#pragma unroll
            for (int ct = 0; ct < 4; ++ct) {
                half8 bf = *(const half8*)&vSc[(16 * ct + l16) * 64 + hox];
                O[ct] = __builtin_amdgcn_mfma_f32_16x16x32_f16(af, bf, O[ct], 0, 0, 0);
            }
        }
        asm volatile("" ::: "memory");
        cur ^= 1;
    }
#undef STAGE_KV
#undef PLOAD

    // ---- epilogue: reduce lsum; store UNNORMALIZED fp32 partial + lsum ----
    float* Op = Opart + (size_t)jh * NB * SEQ * DM;
    float* Lp = Lpart + (size_t)jh * NH * NB * SEQ;
#pragma unroll
    for (int r = 0; r < 4; ++r) {
#pragma unroll
        for (int m = 1; m < 16; m <<= 1) lsum[r] += __shfl_xor(lsum[r], m);
        const int row = i0 + 16 * w + 4 * quad + r;
        if (l16 == 0) Lp[hb * SEQ + row] = lsum[r];
        float* orow = Op + (size_t)(b * SEQ + row) * DM + h * DH;
#pragma unroll
        for (int ct = 0; ct < 4; ++ct)
            orow[16 * ct + l16] = O[ct][r];
    }
}

// ---------------------------------------------------------------------------
// Combine the two j-half partials: ow16 = (O0 + O1) / (l0 + l1), fp16 out.
// Memory-bound: 16.8 MB read + 4 MB write.
// ---------------------------------------------------------------------------
__global__ __launch_bounds__(256)
void attn_combine(const float* __restrict__ O0, const float* __restrict__ O1,
                  const float* __restrict__ L0, const float* __restrict__ L1,
                  _Float16* __restrict__ Out)
{
    const int e = (blockIdx.x * 256 + threadIdx.x) * 8;   // over NB*SEQ*DM
    const int m = e >> 9;          // b*SEQ + i  (DM = 512)
    const int col = e & 511;
    const int h = col >> 6;
    const int b = m >> 11, i = m & 2047;
    const int li = (h * NB + b) * SEQ + i;
    const float inv = 1.f / (L0[li] + L1[li]);
    float4 a0 = *(const float4*)(O0 + e);
    float4 a1 = *(const float4*)(O0 + e + 4);
    float4 c0 = *(const float4*)(O1 + e);
    float4 c1 = *(const float4*)(O1 + e + 4);
    half8 o;
    o[0] = (_Float16)((a0.x + c0.x) * inv);
    o[1] = (_Float16)((a0.y + c0.y) * inv);
    o[2] = (_Float16)((a0.z + c0.z) * inv);
    o[3] = (_Float16)((a0.w + c0.w) * inv);
    o[4] = (_Float16)((a1.x + c1.x) * inv);
    o[5] = (_Float16)((a1.y + c1.y) * inv);
    o[6] = (_Float16)((a1.z + c1.z) * inv);
    o[7] = (_Float16)((a1.w + c1.w) * inv);
    *(half8*)(Out + e) = o;
}

// ---------------------------------------------------------------------------
// Final projection: C = ow16 @ Wo^T + bo (fp32 out), register-prefetch.
// ---------------------------------------------------------------------------
__global__ __launch_bounds__(256)
void gemm_out(const _Float16* __restrict__ A, const _Float16* __restrict__ Wt,
              const float* __restrict__ bias, float* __restrict__ Out)
{
    __shared__ _Float16 aS[64 * 72];
    __shared__ _Float16 wS[64 * 72];

    const int t = threadIdx.x;
    const int w = t >> 6, lane = t & 63, quad = lane >> 4, l16 = lane & 15;
    const int n0 = blockIdx.x * 64;
    const int m0 = blockIdx.y * 64;
    const int srow = t >> 2, sch = (t & 3) * 16;

    const _Float16* arowp = A + (size_t)(m0 + srow) * DM + sch;
    const _Float16* wrowp = Wt + (size_t)(n0 + srow) * DM + sch;

    floatx4 acc[4];
#pragma unroll
    for (int ct = 0; ct < 4; ++ct) acc[ct] = (floatx4){0.f, 0.f, 0.f, 0.f};

    half8 pa0 = *(const half8*)arowp;
    half8 pa1 = *(const half8*)(arowp + 8);
    half8 pw0 = *(const half8*)wrowp;
    half8 pw1 = *(const half8*)(wrowp + 8);

    for (int k0 = 0; k0 < DM; k0 += 64) {
        __syncthreads();
        *(half8*)&aS[srow * 72 + sch]     = pa0;
        *(half8*)&aS[srow * 72 + sch + 8] = pa1;
        *(half8*)&wS[srow * 72 + sch]     = pw0;
        *(half8*)&wS[srow * 72 + sch + 8] = pw1;
        __syncthreads();
        if (k0 + 64 < DM) {
            pa0 = *(const half8*)(arowp + k0 + 64);
            pa1 = *(const half8*)(arowp + k0 + 72);
            pw0 = *(const half8*)(wrowp + k0 + 64);
            pw1 = *(const half8*)(wrowp + k0 + 72);
        }
#pragma unroll
        for (int kb = 0; kb < 2; ++kb) {
            half8 af = *(const half8*)&aS[(16 * w + l16) * 72 + kb * 32 + quad * 8];
#pragma unroll
            for (int ct = 0; ct < 4; ++ct) {
                half8 bf = *(const half8*)&wS[(16 * ct + l16) * 72 + kb * 32 + quad * 8];
                acc[ct] = __builtin_amdgcn_mfma_f32_16x16x32_f16(af, bf, acc[ct], 0, 0, 0);
            }
        }
    }

#pragma unroll
    for (int ct = 0; ct < 4; ++ct) {
        const int n = n0 + 16 * ct + l16;
        const float bval = bias[n];
#pragma unroll
        for (int r = 0; r < 4; ++r) {
            const int m = m0 + 16 * w + 4 * quad + r;
            Out[(size_t)m * DM + n] = acc[ct][r] + bval;
        }
    }
}

extern "C" void kernel_launch(void* const* d_in, const int* in_sizes, int n_in,
                              void* d_out, int out_size, void* d_ws, size_t ws_size,
                              hipStream_t stream)
{
    (void)in_sizes; (void)n_in; (void)out_size; (void)ws_size;
    const float* x   = (const float*)d_in[0];
    const float* pe  = (const float*)d_in[1];
    const float* Wq  = (const float*)d_in[2];
    const float* bq  = (const float*)d_in[3];
    const float* Wk  = (const float*)d_in[4];
    const float* bk  = (const float*)d_in[5];
    const float* Wv  = (const float*)d_in[6];
    const float* bv  = (const float*)d_in[7];
    const float* Wp  = (const float*)d_in[8];
    const float* Wo  = (const float*)d_in[9];
    const float* bo  = (const float*)d_in[10];
    const float* pbu = (const float*)d_in[11];
    const float* pbv = (const float*)d_in[12];
    float* out = (float*)d_out;

    const size_t nX  = (size_t)NB * SEQ * DM;
    const size_t nPe = (size_t)PLEN * DM;
    const size_t nW  = (size_t)DM * DM;
    const size_t nH  = (size_t)NH * NB * SEQ * DH;
    const size_t nPh = (size_t)NH * PLEN * DH;
    const size_t nL  = (size_t)NH * NB * SEQ;

    _Float16* x16  = (_Float16*)d_ws;
    _Float16* pe16 = x16 + nX;
    _Float16* wt   = pe16 + nPe;            // 5 x 512x512: q,k,v,p,o
    _Float16* qu16 = wt + 5 * nW;
    _Float16* qv16 = qu16 + nH;
    _Float16* k16  = qv16 + nH;
    _Float16* vt16 = k16 + nH;
    _Float16* p16  = vt16 + nH;
    _Float16* ow16 = p16 + nPh;
    float*    opart = (float*)(ow16 + nX);  // 2 x nX fp32 partial O
    float*    lpart = opart + 2 * nX;       // 2 x nL fp32 partial lsum

    dim3 blk(256);
    prep<<<dim3(1024, 1, 7), blk, 0, stream>>>(x, pe, Wq, Wk, Wv, Wp, Wo,
                                               x16, pe16, wt);
    gemm_qkvp<<<dim3(8, 64, 4), blk, 0, stream>>>(x16, pe16, wt,
                                                  bq, bk, bv, pbu, pbv,
                                                  qu16, qv16, k16, vt16, p16);
    relattn_mfma<<<dim3(SEQ / 64, NH, NB * 2), blk, 0, stream>>>(
        qu16, qv16, k16, vt16, p16, opart, lpart);
    attn_combine<<<dim3((unsigned)(nX / (256 * 8))), blk, 0, stream>>>(
        opart, opart + nX, lpart, lpart + nL, ow16);
    gemm_out<<<dim3(8, 64), blk, 0, stream>>>(ow16, wt + 4 * nW, bo, out);
}

// Round 5
// 187.496 us; speedup vs baseline: 1.1998x; 1.1998x over previous
//
#include <hip/hip_runtime.h>

#define DM    512
#define NH    8
#define DH    64
#define SEQ   2048
#define PLEN  4095
#define NB    2
#define ATT_SCALE 0.125f

typedef __attribute__((ext_vector_type(8))) _Float16 half8;
typedef __attribute__((ext_vector_type(4))) float   floatx4;

__device__ __forceinline__ void gll16(const _Float16* g, _Float16* l) {
    __builtin_amdgcn_global_load_lds(
        (const __attribute__((address_space(1))) void*)g,
        (__attribute__((address_space(3))) void*)l, 16, 0, 0);
}

// ---------------------------------------------------------------------------
// prep: z=0 cast x -> x16; z=1 cast pe -> pe16; z=2..6 transpose+cast W
// ---------------------------------------------------------------------------
__global__ __launch_bounds__(256)
void prep(const float* __restrict__ x, const float* __restrict__ pe,
          const float* __restrict__ W0, const float* __restrict__ W1,
          const float* __restrict__ W2, const float* __restrict__ W3,
          const float* __restrict__ W4,
          _Float16* __restrict__ x16, _Float16* __restrict__ pe16,
          _Float16* __restrict__ Wt)
{
    __shared__ _Float16 tile[64 * 72];
    const int z = blockIdx.z;
    const int t = threadIdx.x;

    if (z < 2) {
        const float* src = z ? pe : x;
        _Float16* dst = z ? pe16 : x16;
        const long n = z ? (long)PLEN * DM : (long)NB * SEQ * DM;
        const long i = ((long)blockIdx.x * 256 + t) * 8;
        if (i >= n) return;
        float4 f0 = *(const float4*)(src + i);
        float4 f1 = *(const float4*)(src + i + 4);
        half8 o;
        o[0] = (_Float16)f0.x; o[1] = (_Float16)f0.y;
        o[2] = (_Float16)f0.z; o[3] = (_Float16)f0.w;
        o[4] = (_Float16)f1.x; o[5] = (_Float16)f1.y;
        o[6] = (_Float16)f1.z; o[7] = (_Float16)f1.w;
        *(half8*)(dst + i) = o;
        return;
    }
    if (blockIdx.x >= 64) return;
    const int wz = z - 2;
    const float* W = (wz == 0) ? W0 : (wz == 1) ? W1 : (wz == 2) ? W2
                   : (wz == 3) ? W3 : W4;
    _Float16* dst_base = Wt + (size_t)wz * DM * DM;
    const int n0 = (blockIdx.x & 7) * 64, k0 = (blockIdx.x >> 3) * 64;
    {
        const int kr = t >> 2, nch = (t & 3) * 16;
        const float* src = W + (size_t)(k0 + kr) * DM + n0 + nch;
        float4 f0 = *(const float4*)(src + 0);
        float4 f1 = *(const float4*)(src + 4);
        float4 f2 = *(const float4*)(src + 8);
        float4 f3 = *(const float4*)(src + 12);
        _Float16* trow = &tile[kr * 72 + nch];
        trow[0]  = (_Float16)f0.x; trow[1]  = (_Float16)f0.y;
        trow[2]  = (_Float16)f0.z; trow[3]  = (_Float16)f0.w;
        trow[4]  = (_Float16)f1.x; trow[5]  = (_Float16)f1.y;
        trow[6]  = (_Float16)f1.z; trow[7]  = (_Float16)f1.w;
        trow[8]  = (_Float16)f2.x; trow[9]  = (_Float16)f2.y;
        trow[10] = (_Float16)f2.z; trow[11] = (_Float16)f2.w;
        trow[12] = (_Float16)f3.x; trow[13] = (_Float16)f3.y;
        trow[14] = (_Float16)f3.z; trow[15] = (_Float16)f3.w;
    }
    __syncthreads();
    {
        const int nr = t >> 2, kch = (t & 3) * 16;
        half8 o0, o1;
#pragma unroll
        for (int i = 0; i < 8; ++i) o0[i] = tile[(kch + i) * 72 + nr];
#pragma unroll
        for (int i = 0; i < 8; ++i) o1[i] = tile[(kch + 8 + i) * 72 + nr];
        _Float16* dst = dst_base + (size_t)(n0 + nr) * DM + k0 + kch;
        *(half8*)dst = o0;
        *(half8*)(dst + 8) = o1;
    }
}

// ---------------------------------------------------------------------------
// Fused q/k/v/p projections with register-prefetch pipelining (unchanged).
// ---------------------------------------------------------------------------
__global__ __launch_bounds__(256)
void gemm_qkvp(const _Float16* __restrict__ X, const _Float16* __restrict__ Pe,
               const _Float16* __restrict__ Wt,
               const float* __restrict__ bq, const float* __restrict__ bk,
               const float* __restrict__ bv, const float* __restrict__ bu,
               const float* __restrict__ bvb,
               _Float16* __restrict__ qu16, _Float16* __restrict__ qv16,
               _Float16* __restrict__ k16, _Float16* __restrict__ vt16,
               _Float16* __restrict__ p16)
{
    __shared__ _Float16 aS[64 * 72];
    __shared__ _Float16 wS[64 * 72];

    const int t = threadIdx.x;
    const int w = t >> 6, lane = t & 63, quad = lane >> 4, l16 = lane & 15;
    const int z = blockIdx.z;
    const int n0 = blockIdx.x * 64;
    const int m0 = blockIdx.y * 64;
    const int srow = t >> 2, sch = (t & 3) * 16;
    const _Float16* A = (z == 3) ? Pe : X;
    const _Float16* Wz = Wt + (size_t)z * DM * DM;

    int arow = m0 + srow;
    if (z == 3 && arow > PLEN - 1) arow = PLEN - 1;   // clamp; store guarded
    const _Float16* arowp = A + (size_t)arow * DM + sch;
    const _Float16* wrowp = Wz + (size_t)(n0 + srow) * DM + sch;

    floatx4 acc[4];
#pragma unroll
    for (int ct = 0; ct < 4; ++ct) acc[ct] = (floatx4){0.f, 0.f, 0.f, 0.f};

    half8 pa0 = *(const half8*)arowp;
    half8 pa1 = *(const half8*)(arowp + 8);
    half8 pw0 = *(const half8*)wrowp;
    half8 pw1 = *(const half8*)(wrowp + 8);

    for (int k0 = 0; k0 < DM; k0 += 64) {
        __syncthreads();
        *(half8*)&aS[srow * 72 + sch]     = pa0;
        *(half8*)&aS[srow * 72 + sch + 8] = pa1;
        *(half8*)&wS[srow * 72 + sch]     = pw0;
        *(half8*)&wS[srow * 72 + sch + 8] = pw1;
        __syncthreads();
        if (k0 + 64 < DM) {
            pa0 = *(const half8*)(arowp + k0 + 64);
            pa1 = *(const half8*)(arowp + k0 + 72);
            pw0 = *(const half8*)(wrowp + k0 + 64);
            pw1 = *(const half8*)(wrowp + k0 + 72);
        }
#pragma unroll
        for (int kb = 0; kb < 2; ++kb) {
            half8 af = *(const half8*)&aS[(16 * w + l16) * 72 + kb * 32 + quad * 8];
#pragma unroll
            for (int ct = 0; ct < 4; ++ct) {
                half8 bf = *(const half8*)&wS[(16 * ct + l16) * 72 + kb * 32 + quad * 8];
                acc[ct] = __builtin_amdgcn_mfma_f32_16x16x32_f16(af, bf, acc[ct], 0, 0, 0);
            }
        }
    }

    const int h = n0 >> 6;
    if (z == 0) {
#pragma unroll
        for (int ct = 0; ct < 4; ++ct) {
            const int n = n0 + 16 * ct + l16;
            const float bval = bq[n], uval = bu[n], vval = bvb[n];
#pragma unroll
            for (int r = 0; r < 4; ++r) {
                const int m = m0 + 16 * w + 4 * quad + r;
                const int b = m >> 11, s = m & 2047;
                const size_t dst = ((size_t)((h * NB + b) * SEQ) + s) * DH + (n & 63);
                const float q = acc[ct][r] + bval;
                qu16[dst] = (_Float16)((q + uval) * ATT_SCALE);
                qv16[dst] = (_Float16)((q + vval) * ATT_SCALE);
            }
        }
    } else if (z == 1) {
#pragma unroll
        for (int ct = 0; ct < 4; ++ct) {
            const int n = n0 + 16 * ct + l16;
            const float bval = bk[n];
#pragma unroll
            for (int r = 0; r < 4; ++r) {
                const int m = m0 + 16 * w + 4 * quad + r;
                const int b = m >> 11, s = m & 2047;
                k16[((size_t)((h * NB + b) * SEQ) + s) * DH + (n & 63)] =
                    (_Float16)(acc[ct][r] + bval);
            }
        }
    } else if (z == 2) {
        __syncthreads();
#pragma unroll
        for (int ct = 0; ct < 4; ++ct) {
            const float bval = bv[n0 + 16 * ct + l16];
#pragma unroll
            for (int r = 0; r < 4; ++r)
                aS[(16 * w + 4 * quad + r) * 72 + 16 * ct + l16] =
                    (_Float16)(acc[ct][r] + bval);
        }
        __syncthreads();
        const int b = m0 >> 11, s0 = m0 & 2047;
        const int drow = t >> 2;
        half8 o0, o1;
#pragma unroll
        for (int i = 0; i < 8; ++i) o0[i] = aS[(sch + i) * 72 + drow];
#pragma unroll
        for (int i = 0; i < 8; ++i) o1[i] = aS[(sch + 8 + i) * 72 + drow];
        _Float16* dst = vt16 + ((size_t)((h * NB + b) * DH) + drow) * SEQ + s0 + sch;
        *(half8*)dst = o0;
        *(half8*)(dst + 8) = o1;
    } else {
#pragma unroll
        for (int ct = 0; ct < 4; ++ct) {
            const int n = n0 + 16 * ct + l16;
#pragma unroll
            for (int r = 0; r < 4; ++r) {
                const int m = m0 + 16 * w + 4 * quad + r;
                if (m < PLEN)
                    p16[((size_t)h * PLEN + m) * DH + (n & 63)] = (_Float16)acc[ct][r];
            }
        }
    }
}

// ---------------------------------------------------------------------------
// MFMA flash attention, rel-pos, no-max softmax, j-split 2-way.
// R5 = R4 with the vmcnt race FIXED: each STAGE_* issues 2 global_load_lds
// per WAVE, so outstanding at the PV point is V(2)+K(2)+P(2)=6; the V wait
// must be vmcnt(4) (2 oldest = own V), vmcnt(0) on the last tile. Barrier
// after it makes all waves' V slices visible.
//   * P ring buffer (2x64 rows), K dbuf, V single-buffered.
//   * T in regs; rel-shift gather via ds_bpermute.
// LDS 49 KB -> 3 blocks/CU (12 waves). DS model: 552 cyc/wave-tile.
// ---------------------------------------------------------------------------
__global__ __launch_bounds__(256, 3)
void relattn_mfma(const _Float16* __restrict__ QU,
                  const _Float16* __restrict__ QV,
                  const _Float16* __restrict__ Kp,
                  const _Float16* __restrict__ VT,
                  const _Float16* __restrict__ Pp,
                  float* __restrict__ Opart,
                  float* __restrict__ Lpart)
{
    __shared__ _Float16 kbuf[2 * 4096];   // K dbuf, 64x64 each
    __shared__ _Float16 vbuf[4096];       // V single, 64x64
    __shared__ _Float16 pring[2 * 4096];  // P ring, 2 slots x 64 rows
    __shared__ _Float16 tS[64 * 72];      // probs

    const int t = threadIdx.x;
    const int w = t >> 6, lane = t & 63, quad = lane >> 4, l16 = lane & 15;
    const int i0 = blockIdx.x * 64;
    const int h = blockIdx.y;
    const int b = blockIdx.z & 1, jh = blockIdx.z >> 1;
    const size_t hb = (size_t)(h * NB + b);
    const int cbase = 48 - 16 * w;
    const int jbeg = jh * (SEQ / 2), jend = jbeg + (SEQ / 2);

    half8 qa[2], va[2];
    {
        const _Float16* qrow = QU + (hb * SEQ + i0 + 16 * w + l16) * DH + quad * 8;
        const _Float16* vrow = QV + (hb * SEQ + i0 + 16 * w + l16) * DH + quad * 8;
        qa[0] = *(const half8*)qrow;       qa[1] = *(const half8*)(qrow + 32);
        va[0] = *(const half8*)vrow;       va[1] = *(const half8*)(vrow + 32);
    }

    floatx4 O[4];
    float lsum[4] = {0.f, 0.f, 0.f, 0.f};
#pragma unroll
    for (int ct = 0; ct < 4; ++ct) O[ct] = (floatx4){0.f, 0.f, 0.f, 0.f};

    const _Float16* Kbase = Kp + hb * SEQ * DH;
    const _Float16* Vbase = VT + hb * DH * SEQ;
    const _Float16* Pbase = Pp + (size_t)h * PLEN * DH;
    const int rbase0 = (SEQ - 1) - i0 - 63;   // P window base at j0=0
    const int w0beg  = rbase0 + jbeg;         // ring origin (rel = absrow - w0beg)

    // read-side swizzle constants: row&7 == l16&7 for every fragment read
    const int kx = l16 & 7;
    const int hox0 = ((quad) ^ kx) * 8;        // kb=0 chunk offset (halves)
    const int hox1 = ((4 + quad) ^ kx) * 8;    // kb=1

    // staging geometry (8 rows of 128B per gll16; lane -> row cid*8+(lane>>3))
    const int l3 = lane >> 3, pos = lane & 7;

    // phase-A read constants: window row off = cbase+16*c2+l16 in [0,127];
    // ring slot = parity ^ (off>>6), offset = (off&63)*64
    int prow64[5], pcar[5];
#pragma unroll
    for (int c2 = 0; c2 < 5; ++c2) {
        const int off = cbase + 16 * c2 + l16;
        prow64[c2] = (off & 63) * 64;
        pcar[c2]   = (off >> 6) & 1;
    }

#define STAGE_K(DST, J0)                                                       \
    { _Pragma("unroll") for (int I = 0; I < 2; ++I) {                          \
        const int cid = w * 2 + I;                                             \
        const int row = cid * 8 + l3;                                          \
        gll16(Kbase + (size_t)((J0) + row) * DH + ((pos ^ l3) << 3),           \
              (DST) + cid * 512); } }

#define STAGE_V(J0)                                                            \
    { _Pragma("unroll") for (int I = 0; I < 2; ++I) {                          \
        const int cid = w * 2 + I;                                             \
        const int row = cid * 8 + l3;                                          \
        gll16(Vbase + (size_t)row * SEQ + (J0) + ((pos ^ l3) << 3),            \
              vbuf + cid * 512); } }

#define STAGE_P(RELB)                                                         \
    { _Float16* pdst = pring + ((((RELB) >> 6) & 1) * 4096);                  \
      _Pragma("unroll") for (int I = 0; I < 2; ++I) {                         \
        const int cid = w * 2 + I;                                            \
        int ar = w0beg + (RELB) + cid * 8 + l3;                               \
        if (ar > PLEN - 1) ar = PLEN - 1;                                     \
        gll16(Pbase + (size_t)ar * DH + ((pos ^ l3) << 3),                    \
              pdst + cid * 512); } }

    // prologue: K tile 0; P window halves rel [0,64) and [64,128)
    STAGE_K(kbuf, jbeg);
    STAGE_P(0);
    STAGE_P(64);

    int cur = 0, par = 0;
    for (int j0 = jbeg; j0 < jend; j0 += 64) {
        asm volatile("s_waitcnt vmcnt(0)" ::: "memory");
        __builtin_amdgcn_s_barrier();
        asm volatile("" ::: "memory");

        const _Float16* kS = kbuf + cur * 4096;
        const bool more = (j0 + 64 < jend);

        // issue this tile's V + next tile's K (fly during compute)
        STAGE_V(j0);
        if (more) STAGE_K(kbuf + (cur ^ 1) * 4096, j0 + 64);

        // ---- phase A: T = Qv @ Pwin^T from ring-staged LDS ----
        floatx4 Tacc[5];
#pragma unroll
        for (int c2 = 0; c2 < 5; ++c2) Tacc[c2] = (floatx4){0.f, 0.f, 0.f, 0.f};
#pragma unroll
        for (int c2 = 0; c2 < 5; ++c2) {
            const _Float16* pp = pring + ((pcar[c2] ^ par) * 4096) + prow64[c2];
            half8 bf0 = *(const half8*)(pp + hox0);
            half8 bf1 = *(const half8*)(pp + hox1);
            Tacc[c2] = __builtin_amdgcn_mfma_f32_16x16x32_f16(va[0], bf0, Tacc[c2], 0, 0, 0);
            Tacc[c2] = __builtin_amdgcn_mfma_f32_16x16x32_f16(va[1], bf1, Tacc[c2], 0, 0, 0);
        }

        // all waves done reading the retiring ring slot -> restage it
        asm volatile("" ::: "memory");
        __builtin_amdgcn_s_barrier();
        asm volatile("" ::: "memory");
        if (more) STAGE_P((j0 - jbeg) + 128);

        // ---- phase B: S = Qu @ K^T ----
        floatx4 Sc[4];
#pragma unroll
        for (int ct = 0; ct < 4; ++ct) Sc[ct] = (floatx4){0.f, 0.f, 0.f, 0.f};
#pragma unroll
        for (int ct = 0; ct < 4; ++ct) {
            half8 bf0 = *(const half8*)&kS[(16 * ct + l16) * 64 + hox0];
            half8 bf1 = *(const half8*)&kS[(16 * ct + l16) * 64 + hox1];
            Sc[ct] = __builtin_amdgcn_mfma_f32_16x16x32_f16(qa[0], bf0, Sc[ct], 0, 0, 0);
            Sc[ct] = __builtin_amdgcn_mfma_f32_16x16x32_f16(qa[1], bf1, Sc[ct], 0, 0, 0);
        }

        // ---- rel-shift gather from Tacc registers (fixed-quad 16-lane
        // rotation via ds_bpermute) + exp + lsum ----
#pragma unroll
        for (int r = 0; r < 4; ++r) {
            const int u  = l16 - 4 * quad - r + 15;   // [0,30]
            const int dl = u & 15;
            const int s  = u >> 4;                    // {0,1}
            const int pidx = (((quad << 4) | dl) << 2);
            float rot[5];
#pragma unroll
            for (int c2 = 0; c2 < 5; ++c2)
                rot[c2] = __int_as_float(__builtin_amdgcn_ds_bpermute(
                    pidx, __float_as_int(Tacc[c2][r])));
#pragma unroll
            for (int ct = 0; ct < 4; ++ct) {
                const float tv = s ? rot[ct + 1] : rot[ct];
                const float e = __expf(Sc[ct][r] + tv);
                Sc[ct][r] = e;
                lsum[r] += e;
            }
        }

        // ---- probs -> tS (wave-private rows) ----
#pragma unroll
        for (int ct = 0; ct < 4; ++ct)
#pragma unroll
            for (int r = 0; r < 4; ++r)
                tS[(16 * w + 4 * quad + r) * 72 + 16 * ct + l16] = (_Float16)Sc[ct][r];
        asm volatile("" ::: "memory");

        // ---- wait own V DMA (oldest 2 of 6 outstanding: V,K,P issued in
        // that order), then all-wave barrier so every V slice is visible ----
        if (more) asm volatile("s_waitcnt vmcnt(4)" ::: "memory");
        else      asm volatile("s_waitcnt vmcnt(0)" ::: "memory");
        __builtin_amdgcn_s_barrier();
        asm volatile("" ::: "memory");

        // ---- O += P @ V ----
#pragma unroll
        for (int kb = 0; kb < 2; ++kb) {
            half8 af = *(const half8*)&tS[(16 * w + l16) * 72 + kb * 32 + quad * 8];
            const int hox = kb ? hox1 : hox0;
#pragma unroll
            for (int ct = 0; ct < 4; ++ct) {
                half8 bf = *(const half8*)&vbuf[(16 * ct + l16) * 64 + hox];
                O[ct] = __builtin_amdgcn_mfma_f32_16x16x32_f16(af, bf, O[ct], 0, 0, 0);
            }
        }
        asm volatile("" ::: "memory");
        cur ^= 1; par ^= 1;
    }
#undef STAGE_K
#undef STAGE_V
#undef STAGE_P

    // ---- epilogue: reduce lsum; store UNNORMALIZED fp32 partial + lsum ----
    float* Op = Opart + (size_t)jh * NB * SEQ * DM;
    float* Lp = Lpart + (size_t)jh * NH * NB * SEQ;
#pragma unroll
    for (int r = 0; r < 4; ++r) {
#pragma unroll
        for (int m = 1; m < 16; m <<= 1) lsum[r] += __shfl_xor(lsum[r], m);
        const int row = i0 + 16 * w + 4 * quad + r;
        if (l16 == 0) Lp[hb * SEQ + row] = lsum[r];
        float* orow = Op + (size_t)(b * SEQ + row) * DM + h * DH;
#pragma unroll
        for (int ct = 0; ct < 4; ++ct)
            orow[16 * ct + l16] = O[ct][r];
    }
}

// ---------------------------------------------------------------------------
// Combine the two j-half partials: ow16 = (O0 + O1) / (l0 + l1), fp16 out.
// ---------------------------------------------------------------------------
__global__ __launch_bounds__(256)
void attn_combine(const float* __restrict__ O0, const float* __restrict__ O1,
                  const float* __restrict__ L0, const float* __restrict__ L1,
                  _Float16* __restrict__ Out)
{
    const int e = (blockIdx.x * 256 + threadIdx.x) * 8;   // over NB*SEQ*DM
    const int m = e >> 9;          // b*SEQ + i  (DM = 512)
    const int col = e & 511;
    const int h = col >> 6;
    const int b = m >> 11, i = m & 2047;
    const int li = (h * NB + b) * SEQ + i;
    const float inv = 1.f / (L0[li] + L1[li]);
    float4 a0 = *(const float4*)(O0 + e);
    float4 a1 = *(const float4*)(O0 + e + 4);
    float4 c0 = *(const float4*)(O1 + e);
    float4 c1 = *(const float4*)(O1 + e + 4);
    half8 o;
    o[0] = (_Float16)((a0.x + c0.x) * inv);
    o[1] = (_Float16)((a0.y + c0.y) * inv);
    o[2] = (_Float16)((a0.z + c0.z) * inv);
    o[3] = (_Float16)((a0.w + c0.w) * inv);
    o[4] = (_Float16)((a1.x + c1.x) * inv);
    o[5] = (_Float16)((a1.y + c1.y) * inv);
    o[6] = (_Float16)((a1.z + c1.z) * inv);
    o[7] = (_Float16)((a1.w + c1.w) * inv);
    *(half8*)(Out + e) = o;
}

// ---------------------------------------------------------------------------
// Final projection: C = ow16 @ Wo^T + bo (fp32 out), register-prefetch.
// ---------------------------------------------------------------------------
__global__ __launch_bounds__(256)
void gemm_out(const _Float16* __restrict__ A, const _Float16* __restrict__ Wt,
              const float* __restrict__ bias, float* __restrict__ Out)
{
    __shared__ _Float16 aS[64 * 72];
    __shared__ _Float16 wS[64 * 72];

    const int t = threadIdx.x;
    const int w = t >> 6, lane = t & 63, quad = lane >> 4, l16 = lane & 15;
    const int n0 = blockIdx.x * 64;
    const int m0 = blockIdx.y * 64;
    const int srow = t >> 2, sch = (t & 3) * 16;

    const _Float16* arowp = A + (size_t)(m0 + srow) * DM + sch;
    const _Float16* wrowp = Wt + (size_t)(n0 + srow) * DM + sch;

    floatx4 acc[4];
#pragma unroll
    for (int ct = 0; ct < 4; ++ct) acc[ct] = (floatx4){0.f, 0.f, 0.f, 0.f};

    half8 pa0 = *(const half8*)arowp;
    half8 pa1 = *(const half8*)(arowp + 8);
    half8 pw0 = *(const half8*)wrowp;
    half8 pw1 = *(const half8*)(wrowp + 8);

    for (int k0 = 0; k0 < DM; k0 += 64) {
        __syncthreads();
        *(half8*)&aS[srow * 72 + sch]     = pa0;
        *(half8*)&aS[srow * 72 + sch + 8] = pa1;
        *(half8*)&wS[srow * 72 + sch]     = pw0;
        *(half8*)&wS[srow * 72 + sch + 8] = pw1;
        __syncthreads();
        if (k0 + 64 < DM) {
            pa0 = *(const half8*)(arowp + k0 + 64);
            pa1 = *(const half8*)(arowp + k0 + 72);
            pw0 = *(const half8*)(wrowp + k0 + 64);
            pw1 = *(const half8*)(wrowp + k0 + 72);
        }
#pragma unroll
        for (int kb = 0; kb < 2; ++kb) {
            half8 af = *(const half8*)&aS[(16 * w + l16) * 72 + kb * 32 + quad * 8];
#pragma unroll
            for (int ct = 0; ct < 4; ++ct) {
                half8 bf = *(const half8*)&wS[(16 * ct + l16) * 72 + kb * 32 + quad * 8];
                acc[ct] = __builtin_amdgcn_mfma_f32_16x16x32_f16(af, bf, acc[ct], 0, 0, 0);
            }
        }
    }

#pragma unroll
    for (int ct = 0; ct < 4; ++ct) {
        const int n = n0 + 16 * ct + l16;
        const float bval = bias[n];
#pragma unroll
        for (int r = 0; r < 4; ++r) {
            const int m = m0 + 16 * w + 4 * quad + r;
            Out[(size_t)m * DM + n] = acc[ct][r] + bval;
        }
    }
}

extern "C" void kernel_launch(void* const* d_in, const int* in_sizes, int n_in,
                              void* d_out, int out_size, void* d_ws, size_t ws_size,
                              hipStream_t stream)
{
    (void)in_sizes; (void)n_in; (void)out_size; (void)ws_size;
    const float* x   = (const float*)d_in[0];
    const float* pe  = (const float*)d_in[1];
    const float* Wq  = (const float*)d_in[2];
    const float* bq  = (const float*)d_in[3];
    const float* Wk  = (const float*)d_in[4];
    const float* bk  = (const float*)d_in[5];
    const float* Wv  = (const float*)d_in[6];
    const float* bv  = (const float*)d_in[7];
    const float* Wp  = (const float*)d_in[8];
    const float* Wo  = (const float*)d_in[9];
    const float* bo  = (const float*)d_in[10];
    const float* pbu = (const float*)d_in[11];
    const float* pbv = (const float*)d_in[12];
    float* out = (float*)d_out;

    const size_t nX  = (size_t)NB * SEQ * DM;
    const size_t nPe = (size_t)PLEN * DM;
    const size_t nW  = (size_t)DM * DM;
    const size_t nH  = (size_t)NH * NB * SEQ * DH;
    const size_t nPh = (size_t)NH * PLEN * DH;
    const size_t nL  = (size_t)NH * NB * SEQ;

    _Float16* x16  = (_Float16*)d_ws;
    _Float16* pe16 = x16 + nX;
    _Float16* wt   = pe16 + nPe;            // 5 x 512x512: q,k,v,p,o
    _Float16* qu16 = wt + 5 * nW;
    _Float16* qv16 = qu16 + nH;
    _Float16* k16  = qv16 + nH;
    _Float16* vt16 = k16 + nH;
    _Float16* p16  = vt16 + nH;
    _Float16* ow16 = p16 + nPh;
    float*    opart = (float*)(ow16 + nX);  // 2 x nX fp32 partial O
    float*    lpart = opart + 2 * nX;       // 2 x nL fp32 partial lsum

    dim3 blk(256);
    prep<<<dim3(1024, 1, 7), blk, 0, stream>>>(x, pe, Wq, Wk, Wv, Wp, Wo,
                                               x16, pe16, wt);
    gemm_qkvp<<<dim3(8, 64, 4), blk, 0, stream>>>(x16, pe16, wt,
                                                  bq, bk, bv, pbu, pbv,
                                                  qu16, qv16, k16, vt16, p16);
    relattn_mfma<<<dim3(SEQ / 64, NH, NB * 2), blk, 0, stream>>>(
        qu16, qv16, k16, vt16, p16, opart, lpart);
    attn_combine<<<dim3((unsigned)(nX / (256 * 8))), blk, 0, stream>>>(
        opart, opart + nX, lpart, lpart + nL, ow16);
    gemm_out<<<dim3(8, 64), blk, 0, stream>>>(ow16, wt + 4 * nW, bo, out);
}

// Round 6
// 178.261 us; speedup vs baseline: 1.2619x; 1.0518x over previous
//
#include <hip/hip_runtime.h>

#define DM    512
#define NH    8
#define DH    64
#define SEQ   2048
#define PLEN  4095
#define NB    2
#define ATT_SCALE 0.125f

typedef __attribute__((ext_vector_type(8))) _Float16 half8;
typedef __attribute__((ext_vector_type(4))) float   floatx4;

__device__ __forceinline__ void gll16(const _Float16* g, _Float16* l) {
    __builtin_amdgcn_global_load_lds(
        (const __attribute__((address_space(1))) void*)g,
        (__attribute__((address_space(3))) void*)l, 16, 0, 0);
}

// ---------------------------------------------------------------------------
// prep: z=0 cast x -> x16; z=1 cast pe -> pe16; z=2..6 transpose+cast W
// ---------------------------------------------------------------------------
__global__ __launch_bounds__(256)
void prep(const float* __restrict__ x, const float* __restrict__ pe,
          const float* __restrict__ W0, const float* __restrict__ W1,
          const float* __restrict__ W2, const float* __restrict__ W3,
          const float* __restrict__ W4,
          _Float16* __restrict__ x16, _Float16* __restrict__ pe16,
          _Float16* __restrict__ Wt)
{
    __shared__ _Float16 tile[64 * 72];
    const int z = blockIdx.z;
    const int t = threadIdx.x;

    if (z < 2) {
        const float* src = z ? pe : x;
        _Float16* dst = z ? pe16 : x16;
        const long n = z ? (long)PLEN * DM : (long)NB * SEQ * DM;
        const long i = ((long)blockIdx.x * 256 + t) * 8;
        if (i >= n) return;
        float4 f0 = *(const float4*)(src + i);
        float4 f1 = *(const float4*)(src + i + 4);
        half8 o;
        o[0] = (_Float16)f0.x; o[1] = (_Float16)f0.y;
        o[2] = (_Float16)f0.z; o[3] = (_Float16)f0.w;
        o[4] = (_Float16)f1.x; o[5] = (_Float16)f1.y;
        o[6] = (_Float16)f1.z; o[7] = (_Float16)f1.w;
        *(half8*)(dst + i) = o;
        return;
    }
    if (blockIdx.x >= 64) return;
    const int wz = z - 2;
    const float* W = (wz == 0) ? W0 : (wz == 1) ? W1 : (wz == 2) ? W2
                   : (wz == 3) ? W3 : W4;
    _Float16* dst_base = Wt + (size_t)wz * DM * DM;
    const int n0 = (blockIdx.x & 7) * 64, k0 = (blockIdx.x >> 3) * 64;
    {
        const int kr = t >> 2, nch = (t & 3) * 16;
        const float* src = W + (size_t)(k0 + kr) * DM + n0 + nch;
        float4 f0 = *(const float4*)(src + 0);
        float4 f1 = *(const float4*)(src + 4);
        float4 f2 = *(const float4*)(src + 8);
        float4 f3 = *(const float4*)(src + 12);
        _Float16* trow = &tile[kr * 72 + nch];
        trow[0]  = (_Float16)f0.x; trow[1]  = (_Float16)f0.y;
        trow[2]  = (_Float16)f0.z; trow[3]  = (_Float16)f0.w;
        trow[4]  = (_Float16)f1.x; trow[5]  = (_Float16)f1.y;
        trow[6]  = (_Float16)f1.z; trow[7]  = (_Float16)f1.w;
        trow[8]  = (_Float16)f2.x; trow[9]  = (_Float16)f2.y;
        trow[10] = (_Float16)f2.z; trow[11] = (_Float16)f2.w;
        trow[12] = (_Float16)f3.x; trow[13] = (_Float16)f3.y;
        trow[14] = (_Float16)f3.z; trow[15] = (_Float16)f3.w;
    }
    __syncthreads();
    {
        const int nr = t >> 2, kch = (t & 3) * 16;
        half8 o0, o1;
#pragma unroll
        for (int i = 0; i < 8; ++i) o0[i] = tile[(kch + i) * 72 + nr];
#pragma unroll
        for (int i = 0; i < 8; ++i) o1[i] = tile[(kch + 8 + i) * 72 + nr];
        _Float16* dst = dst_base + (size_t)(n0 + nr) * DM + k0 + kch;
        *(half8*)dst = o0;
        *(half8*)(dst + 8) = o1;
    }
}

// ---------------------------------------------------------------------------
// Fused q/k/v/p projections, R6: 128x128 tile, BK=64, m97-style structure.
// 4 waves, each owns a 64x64 quadrant (acc[4][4]); staging via
// global_load_lds (width 16) into XOR-swizzled linear LDS, double-buffered
// (64 KB -> 2 blocks/CU, grid 512 = exact residency).
//   z=0: qu/qv  z=1: k16  z=2: vt16 (LDS transpose epi)  z=3: p16 (clamped)
// ---------------------------------------------------------------------------
__global__ __launch_bounds__(256)
void gemm_qkvp(const _Float16* __restrict__ X, const _Float16* __restrict__ Pe,
               const _Float16* __restrict__ Wt,
               const float* __restrict__ bq, const float* __restrict__ bk,
               const float* __restrict__ bv, const float* __restrict__ bu,
               const float* __restrict__ bvb,
               _Float16* __restrict__ qu16, _Float16* __restrict__ qv16,
               _Float16* __restrict__ k16, _Float16* __restrict__ vt16,
               _Float16* __restrict__ p16)
{
    __shared__ _Float16 smem[32768];   // [2][ A 128x64 | W 128x64 ]

    const int t = threadIdx.x;
    const int w = t >> 6, lane = t & 63, quad = lane >> 4, l16 = lane & 15;
    const int wr = w >> 1, wc = w & 1;
    const int l3 = lane >> 3, pos = lane & 7;
    const int z = blockIdx.z;
    const int n0 = blockIdx.x * 128;
    const int m0 = blockIdx.y * 128;

    const _Float16* A = (z == 3) ? Pe : X;
    const _Float16* Wz = Wt + (size_t)z * DM * DM;

    const int kx = l16 & 7;
    const int hox0 = ((quad) ^ kx) * 8;
    const int hox1 = ((4 + quad) ^ kx) * 8;

    floatx4 acc[4][4];
#pragma unroll
    for (int i = 0; i < 4; ++i)
#pragma unroll
        for (int j = 0; j < 4; ++j) acc[i][j] = (floatx4){0.f, 0.f, 0.f, 0.f};

#define QSTAGE(CUR, K0)                                                        \
    { _Float16* aB = smem + (CUR) * 16384;                                     \
      _Float16* wB = aB + 8192;                                                \
      _Pragma("unroll") for (int I = 0; I < 4; ++I) {                          \
        const int gr = I * 32 + w * 8 + l3;                                    \
        const int ch = pos ^ l3;                                               \
        int ar = m0 + gr; if (z == 3 && ar > PLEN - 1) ar = PLEN - 1;          \
        gll16(A + (size_t)ar * DM + (K0) + ch * 8, aB + I * 2048 + w * 512);   \
        gll16(Wz + (size_t)(n0 + gr) * DM + (K0) + ch * 8,                     \
              wB + I * 2048 + w * 512); } }

    QSTAGE(0, 0);
    int cur = 0;
    for (int k0 = 0; k0 < DM; k0 += 64) {
        asm volatile("s_waitcnt vmcnt(0)" ::: "memory");
        __builtin_amdgcn_s_barrier();
        asm volatile("" ::: "memory");
        if (k0 + 64 < DM) QSTAGE(cur ^ 1, k0 + 64);
        const _Float16* aB = smem + cur * 16384;
        const _Float16* wB = aB + 8192;
#pragma unroll
        for (int kb = 0; kb < 2; ++kb) {
            const int hox = kb ? hox1 : hox0;
            half8 af[4], bf[4];
#pragma unroll
            for (int i = 0; i < 4; ++i)
                af[i] = *(const half8*)&aB[(wr * 64 + i * 16 + l16) * 64 + hox];
#pragma unroll
            for (int j = 0; j < 4; ++j)
                bf[j] = *(const half8*)&wB[(wc * 64 + j * 16 + l16) * 64 + hox];
#pragma unroll
            for (int i = 0; i < 4; ++i)
#pragma unroll
                for (int j = 0; j < 4; ++j)
                    acc[i][j] = __builtin_amdgcn_mfma_f32_16x16x32_f16(
                        af[i], bf[j], acc[i][j], 0, 0, 0);
        }
        cur ^= 1;
    }
#undef QSTAGE

    // ---- epilogues (index algebra carried over from the verified 64² code) ----
    const int hh = (n0 >> 6) + wc;          // head of this wave's quadrant
    const int bb = m0 >> 11;                // batch (uniform: 128 | 2048)
    const int sbase = (m0 & 2047) + wr * 64;

    if (z == 0) {
#pragma unroll
        for (int j = 0; j < 4; ++j) {
            const int n = n0 + wc * 64 + j * 16 + l16;
            const int d = j * 16 + l16 - (wc ? 64 : 0) + (wc ? 64 : 0);  // = n&63
            const float bval = bq[n], uval = bu[n], vval = bvb[n];
#pragma unroll
            for (int i = 0; i < 4; ++i)
#pragma unroll
                for (int r = 0; r < 4; ++r) {
                    const int s = sbase + i * 16 + 4 * quad + r;
                    const size_t dst = ((size_t)((hh * NB + bb) * SEQ) + s) * DH + (n & 63);
                    const float q = acc[i][j][r] + bval;
                    qu16[dst] = (_Float16)((q + uval) * ATT_SCALE);
                    qv16[dst] = (_Float16)((q + vval) * ATT_SCALE);
                }
            (void)d;
        }
    } else if (z == 1) {
#pragma unroll
        for (int j = 0; j < 4; ++j) {
            const int n = n0 + wc * 64 + j * 16 + l16;
            const float bval = bk[n];
#pragma unroll
            for (int i = 0; i < 4; ++i)
#pragma unroll
                for (int r = 0; r < 4; ++r) {
                    const int s = sbase + i * 16 + 4 * quad + r;
                    k16[((size_t)((hh * NB + bb) * SEQ) + s) * DH + (n & 63)] =
                        (_Float16)(acc[i][j][r] + bval);
                }
        }
    } else if (z == 2) {
        // transpose epilogue through (now-free) staging LDS, stride 132
        __syncthreads();
        _Float16* tr = smem;
#pragma unroll
        for (int j = 0; j < 4; ++j) {
            const int ncol = wc * 64 + j * 16 + l16;
            const float bval = bv[n0 + ncol];
#pragma unroll
            for (int i = 0; i < 4; ++i)
#pragma unroll
                for (int r = 0; r < 4; ++r)
                    tr[(wr * 64 + i * 16 + 4 * quad + r) * 132 + ncol] =
                        (_Float16)(acc[i][j][r] + bval);
        }
        __syncthreads();
        {
            const int col = t >> 1;             // n-local 0..127
            const int half = t & 1;             // s-chunk
            const int h2 = (n0 + col) >> 6, d = (n0 + col) & 63;
            const int s0 = (m0 & 2047) + half * 64;
            _Float16* dst = vt16 + ((size_t)((h2 * NB + bb) * DH) + d) * SEQ + s0;
#pragma unroll
            for (int c = 0; c < 8; ++c) {
                half8 o;
#pragma unroll
                for (int k = 0; k < 8; ++k)
                    o[k] = tr[(half * 64 + c * 8 + k) * 132 + col];
                *(half8*)(dst + c * 8) = o;
            }
        }
    } else {
#pragma unroll
        for (int j = 0; j < 4; ++j) {
            const int n = n0 + wc * 64 + j * 16 + l16;
#pragma unroll
            for (int i = 0; i < 4; ++i)
#pragma unroll
                for (int r = 0; r < 4; ++r) {
                    const int m = m0 + wr * 64 + i * 16 + 4 * quad + r;
                    if (m < PLEN)
                        p16[((size_t)hh * PLEN + m) * DH + (n & 63)] =
                            (_Float16)acc[i][j][r];
                }
        }
    }
}

// ---------------------------------------------------------------------------
// MFMA flash attention, rel-pos, no-max softmax, j-split 2-way (R5, verified).
// ---------------------------------------------------------------------------
__global__ __launch_bounds__(256, 3)
void relattn_mfma(const _Float16* __restrict__ QU,
                  const _Float16* __restrict__ QV,
                  const _Float16* __restrict__ Kp,
                  const _Float16* __restrict__ VT,
                  const _Float16* __restrict__ Pp,
                  float* __restrict__ Opart,
                  float* __restrict__ Lpart)
{
    __shared__ _Float16 kbuf[2 * 4096];   // K dbuf, 64x64 each
    __shared__ _Float16 vbuf[4096];       // V single, 64x64
    __shared__ _Float16 pring[2 * 4096];  // P ring, 2 slots x 64 rows
    __shared__ _Float16 tS[64 * 72];      // probs

    const int t = threadIdx.x;
    const int w = t >> 6, lane = t & 63, quad = lane >> 4, l16 = lane & 15;
    const int i0 = blockIdx.x * 64;
    const int h = blockIdx.y;
    const int b = blockIdx.z & 1, jh = blockIdx.z >> 1;
    const size_t hb = (size_t)(h * NB + b);
    const int cbase = 48 - 16 * w;
    const int jbeg = jh * (SEQ / 2), jend = jbeg + (SEQ / 2);

    half8 qa[2], va[2];
    {
        const _Float16* qrow = QU + (hb * SEQ + i0 + 16 * w + l16) * DH + quad * 8;
        const _Float16* vrow = QV + (hb * SEQ + i0 + 16 * w + l16) * DH + quad * 8;
        qa[0] = *(const half8*)qrow;       qa[1] = *(const half8*)(qrow + 32);
        va[0] = *(const half8*)vrow;       va[1] = *(const half8*)(vrow + 32);
    }

    floatx4 O[4];
    float lsum[4] = {0.f, 0.f, 0.f, 0.f};
#pragma unroll
    for (int ct = 0; ct < 4; ++ct) O[ct] = (floatx4){0.f, 0.f, 0.f, 0.f};

    const _Float16* Kbase = Kp + hb * SEQ * DH;
    const _Float16* Vbase = VT + hb * DH * SEQ;
    const _Float16* Pbase = Pp + (size_t)h * PLEN * DH;
    const int rbase0 = (SEQ - 1) - i0 - 63;   // P window base at j0=0
    const int w0beg  = rbase0 + jbeg;         // ring origin (rel = absrow - w0beg)

    const int kx = l16 & 7;
    const int hox0 = ((quad) ^ kx) * 8;
    const int hox1 = ((4 + quad) ^ kx) * 8;

    const int l3 = lane >> 3, pos = lane & 7;

    int prow64[5], pcar[5];
#pragma unroll
    for (int c2 = 0; c2 < 5; ++c2) {
        const int off = cbase + 16 * c2 + l16;
        prow64[c2] = (off & 63) * 64;
        pcar[c2]   = (off >> 6) & 1;
    }

#define STAGE_K(DST, J0)                                                       \
    { _Pragma("unroll") for (int I = 0; I < 2; ++I) {                          \
        const int cid = w * 2 + I;                                             \
        const int row = cid * 8 + l3;                                          \
        gll16(Kbase + (size_t)((J0) + row) * DH + ((pos ^ l3) << 3),           \
              (DST) + cid * 512); } }

#define STAGE_V(J0)                                                            \
    { _Pragma("unroll") for (int I = 0; I < 2; ++I) {                          \
        const int cid = w * 2 + I;                                             \
        const int row = cid * 8 + l3;                                          \
        gll16(Vbase + (size_t)row * SEQ + (J0) + ((pos ^ l3) << 3),            \
              vbuf + cid * 512); } }

#define STAGE_P(RELB)                                                         \
    { _Float16* pdst = pring + ((((RELB) >> 6) & 1) * 4096);                  \
      _Pragma("unroll") for (int I = 0; I < 2; ++I) {                         \
        const int cid = w * 2 + I;                                            \
        int ar = w0beg + (RELB) + cid * 8 + l3;                               \
        if (ar > PLEN - 1) ar = PLEN - 1;                                     \
        gll16(Pbase + (size_t)ar * DH + ((pos ^ l3) << 3),                    \
              pdst + cid * 512); } }

    STAGE_K(kbuf, jbeg);
    STAGE_P(0);
    STAGE_P(64);

    int cur = 0, par = 0;
    for (int j0 = jbeg; j0 < jend; j0 += 64) {
        asm volatile("s_waitcnt vmcnt(0)" ::: "memory");
        __builtin_amdgcn_s_barrier();
        asm volatile("" ::: "memory");

        const _Float16* kS = kbuf + cur * 4096;
        const bool more = (j0 + 64 < jend);

        STAGE_V(j0);
        if (more) STAGE_K(kbuf + (cur ^ 1) * 4096, j0 + 64);

        // ---- phase A: T = Qv @ Pwin^T from ring-staged LDS ----
        floatx4 Tacc[5];
#pragma unroll
        for (int c2 = 0; c2 < 5; ++c2) Tacc[c2] = (floatx4){0.f, 0.f, 0.f, 0.f};
#pragma unroll
        for (int c2 = 0; c2 < 5; ++c2) {
            const _Float16* pp = pring + ((pcar[c2] ^ par) * 4096) + prow64[c2];
            half8 bf0 = *(const half8*)(pp + hox0);
            half8 bf1 = *(const half8*)(pp + hox1);
            Tacc[c2] = __builtin_amdgcn_mfma_f32_16x16x32_f16(va[0], bf0, Tacc[c2], 0, 0, 0);
            Tacc[c2] = __builtin_amdgcn_mfma_f32_16x16x32_f16(va[1], bf1, Tacc[c2], 0, 0, 0);
        }

        asm volatile("" ::: "memory");
        __builtin_amdgcn_s_barrier();
        asm volatile("" ::: "memory");
        if (more) STAGE_P((j0 - jbeg) + 128);

        // ---- phase B: S = Qu @ K^T ----
        floatx4 Sc[4];
#pragma unroll
        for (int ct = 0; ct < 4; ++ct) Sc[ct] = (floatx4){0.f, 0.f, 0.f, 0.f};
#pragma unroll
        for (int ct = 0; ct < 4; ++ct) {
            half8 bf0 = *(const half8*)&kS[(16 * ct + l16) * 64 + hox0];
            half8 bf1 = *(const half8*)&kS[(16 * ct + l16) * 64 + hox1];
            Sc[ct] = __builtin_amdgcn_mfma_f32_16x16x32_f16(qa[0], bf0, Sc[ct], 0, 0, 0);
            Sc[ct] = __builtin_amdgcn_mfma_f32_16x16x32_f16(qa[1], bf1, Sc[ct], 0, 0, 0);
        }

        // ---- rel-shift gather + exp + lsum ----
#pragma unroll
        for (int r = 0; r < 4; ++r) {
            const int u  = l16 - 4 * quad - r + 15;   // [0,30]
            const int dl = u & 15;
            const int s  = u >> 4;                    // {0,1}
            const int pidx = (((quad << 4) | dl) << 2);
            float rot[5];
#pragma unroll
            for (int c2 = 0; c2 < 5; ++c2)
                rot[c2] = __int_as_float(__builtin_amdgcn_ds_bpermute(
                    pidx, __float_as_int(Tacc[c2][r])));
#pragma unroll
            for (int ct = 0; ct < 4; ++ct) {
                const float tv = s ? rot[ct + 1] : rot[ct];
                const float e = __expf(Sc[ct][r] + tv);
                Sc[ct][r] = e;
                lsum[r] += e;
            }
        }

        // ---- probs -> tS (wave-private rows) ----
#pragma unroll
        for (int ct = 0; ct < 4; ++ct)
#pragma unroll
            for (int r = 0; r < 4; ++r)
                tS[(16 * w + 4 * quad + r) * 72 + 16 * ct + l16] = (_Float16)Sc[ct][r];
        asm volatile("" ::: "memory");

        // ---- wait own V DMA (oldest 2 of 6), then all-wave barrier ----
        if (more) asm volatile("s_waitcnt vmcnt(4)" ::: "memory");
        else      asm volatile("s_waitcnt vmcnt(0)" ::: "memory");
        __builtin_amdgcn_s_barrier();
        asm volatile("" ::: "memory");

        // ---- O += P @ V ----
#pragma unroll
        for (int kb = 0; kb < 2; ++kb) {
            half8 af = *(const half8*)&tS[(16 * w + l16) * 72 + kb * 32 + quad * 8];
            const int hox = kb ? hox1 : hox0;
#pragma unroll
            for (int ct = 0; ct < 4; ++ct) {
                half8 bf = *(const half8*)&vbuf[(16 * ct + l16) * 64 + hox];
                O[ct] = __builtin_amdgcn_mfma_f32_16x16x32_f16(af, bf, O[ct], 0, 0, 0);
            }
        }
        asm volatile("" ::: "memory");
        cur ^= 1; par ^= 1;
    }
#undef STAGE_K
#undef STAGE_V
#undef STAGE_P

    float* Op = Opart + (size_t)jh * NB * SEQ * DM;
    float* Lp = Lpart + (size_t)jh * NH * NB * SEQ;
#pragma unroll
    for (int r = 0; r < 4; ++r) {
#pragma unroll
        for (int m = 1; m < 16; m <<= 1) lsum[r] += __shfl_xor(lsum[r], m);
        const int row = i0 + 16 * w + 4 * quad + r;
        if (l16 == 0) Lp[hb * SEQ + row] = lsum[r];
        float* orow = Op + (size_t)(b * SEQ + row) * DM + h * DH;
#pragma unroll
        for (int ct = 0; ct < 4; ++ct)
            orow[16 * ct + l16] = O[ct][r];
    }
}

// ---------------------------------------------------------------------------
// Combine the two j-half partials: ow16 = (O0 + O1) / (l0 + l1), fp16 out.
// ---------------------------------------------------------------------------
__global__ __launch_bounds__(256)
void attn_combine(const float* __restrict__ O0, const float* __restrict__ O1,
                  const float* __restrict__ L0, const float* __restrict__ L1,
                  _Float16* __restrict__ Out)
{
    const int e = (blockIdx.x * 256 + threadIdx.x) * 8;   // over NB*SEQ*DM
    const int m = e >> 9;          // b*SEQ + i  (DM = 512)
    const int col = e & 511;
    const int h = col >> 6;
    const int b = m >> 11, i = m & 2047;
    const int li = (h * NB + b) * SEQ + i;
    const float inv = 1.f / (L0[li] + L1[li]);
    float4 a0 = *(const float4*)(O0 + e);
    float4 a1 = *(const float4*)(O0 + e + 4);
    float4 c0 = *(const float4*)(O1 + e);
    float4 c1 = *(const float4*)(O1 + e + 4);
    half8 o;
    o[0] = (_Float16)((a0.x + c0.x) * inv);
    o[1] = (_Float16)((a0.y + c0.y) * inv);
    o[2] = (_Float16)((a0.z + c0.z) * inv);
    o[3] = (_Float16)((a0.w + c0.w) * inv);
    o[4] = (_Float16)((a1.x + c1.x) * inv);
    o[5] = (_Float16)((a1.y + c1.y) * inv);
    o[6] = (_Float16)((a1.z + c1.z) * inv);
    o[7] = (_Float16)((a1.w + c1.w) * inv);
    *(half8*)(Out + e) = o;
}

// ---------------------------------------------------------------------------
// Final projection: C = ow16 @ Wo^T + bo (fp32 out), register-prefetch.
// ---------------------------------------------------------------------------
__global__ __launch_bounds__(256)
void gemm_out(const _Float16* __restrict__ A, const _Float16* __restrict__ Wt,
              const float* __restrict__ bias, float* __restrict__ Out)
{
    __shared__ _Float16 aS[64 * 72];
    __shared__ _Float16 wS[64 * 72];

    const int t = threadIdx.x;
    const int w = t >> 6, lane = t & 63, quad = lane >> 4, l16 = lane & 15;
    const int n0 = blockIdx.x * 64;
    const int m0 = blockIdx.y * 64;
    const int srow = t >> 2, sch = (t & 3) * 16;

    const _Float16* arowp = A + (size_t)(m0 + srow) * DM + sch;
    const _Float16* wrowp = Wt + (size_t)(n0 + srow) * DM + sch;

    floatx4 acc[4];
#pragma unroll
    for (int ct = 0; ct < 4; ++ct) acc[ct] = (floatx4){0.f, 0.f, 0.f, 0.f};

    half8 pa0 = *(const half8*)arowp;
    half8 pa1 = *(const half8*)(arowp + 8);
    half8 pw0 = *(const half8*)wrowp;
    half8 pw1 = *(const half8*)(wrowp + 8);

    for (int k0 = 0; k0 < DM; k0 += 64) {
        __syncthreads();
        *(half8*)&aS[srow * 72 + sch]     = pa0;
        *(half8*)&aS[srow * 72 + sch + 8] = pa1;
        *(half8*)&wS[srow * 72 + sch]     = pw0;
        *(half8*)&wS[srow * 72 + sch + 8] = pw1;
        __syncthreads();
        if (k0 + 64 < DM) {
            pa0 = *(const half8*)(arowp + k0 + 64);
            pa1 = *(const half8*)(arowp + k0 + 72);
            pw0 = *(const half8*)(wrowp + k0 + 64);
            pw1 = *(const half8*)(wrowp + k0 + 72);
        }
#pragma unroll
        for (int kb = 0; kb < 2; ++kb) {
            half8 af = *(const half8*)&aS[(16 * w + l16) * 72 + kb * 32 + quad * 8];
#pragma unroll
            for (int ct = 0; ct < 4; ++ct) {
                half8 bf = *(const half8*)&wS[(16 * ct + l16) * 72 + kb * 32 + quad * 8];
                acc[ct] = __builtin_amdgcn_mfma_f32_16x16x32_f16(af, bf, acc[ct], 0, 0, 0);
            }
        }
    }

#pragma unroll
    for (int ct = 0; ct < 4; ++ct) {
        const int n = n0 + 16 * ct + l16;
        const float bval = bias[n];
#pragma unroll
        for (int r = 0; r < 4; ++r) {
            const int m = m0 + 16 * w + 4 * quad + r;
            Out[(size_t)m * DM + n] = acc[ct][r] + bval;
        }
    }
}

extern "C" void kernel_launch(void* const* d_in, const int* in_sizes, int n_in,
                              void* d_out, int out_size, void* d_ws, size_t ws_size,
                              hipStream_t stream)
{
    (void)in_sizes; (void)n_in; (void)out_size; (void)ws_size;
    const float* x   = (const float*)d_in[0];
    const float* pe  = (const float*)d_in[1];
    const float* Wq  = (const float*)d_in[2];
    const float* bq  = (const float*)d_in[3];
    const float* Wk  = (const float*)d_in[4];
    const float* bk  = (const float*)d_in[5];
    const float* Wv  = (const float*)d_in[6];
    const float* bv  = (const float*)d_in[7];
    const float* Wp  = (const float*)d_in[8];
    const float* Wo  = (const float*)d_in[9];
    const float* bo  = (const float*)d_in[10];
    const float* pbu = (const float*)d_in[11];
    const float* pbv = (const float*)d_in[12];
    float* out = (float*)d_out;

    const size_t nX  = (size_t)NB * SEQ * DM;
    const size_t nPe = (size_t)PLEN * DM;
    const size_t nW  = (size_t)DM * DM;
    const size_t nH  = (size_t)NH * NB * SEQ * DH;
    const size_t nPh = (size_t)NH * PLEN * DH;
    const size_t nL  = (size_t)NH * NB * SEQ;

    _Float16* x16  = (_Float16*)d_ws;
    _Float16* pe16 = x16 + nX;
    _Float16* wt   = pe16 + nPe;            // 5 x 512x512: q,k,v,p,o
    _Float16* qu16 = wt + 5 * nW;
    _Float16* qv16 = qu16 + nH;
    _Float16* k16  = qv16 + nH;
    _Float16* vt16 = k16 + nH;
    _Float16* p16  = vt16 + nH;
    _Float16* ow16 = p16 + nPh;
    float*    opart = (float*)(ow16 + nX);  // 2 x nX fp32 partial O
    float*    lpart = opart + 2 * nX;       // 2 x nL fp32 partial lsum

    dim3 blk(256);
    prep<<<dim3(1024, 1, 7), blk, 0, stream>>>(x, pe, Wq, Wk, Wv, Wp, Wo,
                                               x16, pe16, wt);
    gemm_qkvp<<<dim3(4, 32, 4), blk, 0, stream>>>(x16, pe16, wt,
                                                  bq, bk, bv, pbu, pbv,
                                                  qu16, qv16, k16, vt16, p16);
    relattn_mfma<<<dim3(SEQ / 64, NH, NB * 2), blk, 0, stream>>>(
        qu16, qv16, k16, vt16, p16, opart, lpart);
    attn_combine<<<dim3((unsigned)(nX / (256 * 8))), blk, 0, stream>>>(
        opart, opart + nX, lpart, lpart + nL, ow16);
    gemm_out<<<dim3(8, 64), blk, 0, stream>>>(ow16, wt + 4 * nW, bo, out);
}